// Round 6
// baseline (1522.030 us; speedup 1.0000x reference)
//
#include <hip/hip_runtime.h>

// ---------------------------------------------------------------------------
// 4-layer transformer decoder, bf16 MFMA implementation (round 6).
// gemm256: 256x256 tile, 8 waves, BK=64, 2-buffer LDS, m201-style phases:
//   {ds_read; stage; s_barrier; lgkmcnt(0); setprio MFMA; counted vmcnt;
//    s_barrier} -- mid-phase barrier overlaps LDS latency with wave sync.
// vmcnt ledger (2 gll/thread/unit, units A_lo,B_lo,B_hi,A_hi staged 1/phase):
// steady-state waits 4/4/none/4, never drained to 0. B_lo frags held in regs
// across the tile (P4 reads nothing).
// ---------------------------------------------------------------------------

typedef __attribute__((ext_vector_type(4))) float f32x4;
typedef __attribute__((ext_vector_type(8))) short bf16x8;
typedef __attribute__((ext_vector_type(4))) unsigned short u16x4;
typedef __attribute__((ext_vector_type(4))) unsigned int   u32x4;

__device__ __forceinline__ unsigned short f2bf(float f) {
    unsigned int u = __builtin_bit_cast(unsigned int, f);
    u += 0x7fffu + ((u >> 16) & 1u);   // RNE
    return (unsigned short)(u >> 16);
}

__device__ __forceinline__ void gll16(const unsigned short* g, unsigned short* l) {
    auto* gp = reinterpret_cast<const __attribute__((address_space(1))) unsigned int*>(
        reinterpret_cast<uintptr_t>(g));
    auto* lp = reinterpret_cast<__attribute__((address_space(3))) unsigned int*>(
        reinterpret_cast<uintptr_t>(l));
    __builtin_amdgcn_global_load_lds(gp, lp, 16, 0, 0);
}

#define SBAR0() __builtin_amdgcn_sched_barrier(0)

// ---------------------------------------------------------------------------
// gemm256: out = epilogue( A(bf16)[M][lda] @ Bw(bf16)[N][lda]^T ), K range
// [kz, kz+klen). 8 waves (2M x 4N), per-wave 128x64 output.
// mode 0: bf16(acc+bias)  1: bf16(relu(acc+bias))  3: raw f32 -> outf{0,1}
// ---------------------------------------------------------------------------
__global__ __launch_bounds__(512, 2) void gemm256(
    const unsigned short* __restrict__ A,
    const unsigned short* __restrict__ Bw,
    const float* __restrict__ bias,
    unsigned short* __restrict__ outb,
    float* __restrict__ outf0,
    float* __restrict__ outf1,
    int N, int lda, int klen, int mode)
{
    __shared__ unsigned short Al[2][256 * 64];
    __shared__ unsigned short Bl[2][256 * 64];
    const int tid  = threadIdx.x;
    const int lane = tid & 63;
    const int wid  = tid >> 6;              // 0..7
    const int wrb  = (wid >> 2) * 128;      // wave row base in tile
    const int wcb  = (wid & 3) * 64;        // wave col base in tile
    const int l15  = lane & 15;
    const int l4   = lane >> 4;
    const int m0   = blockIdx.y * 256;
    const int n0   = blockIdx.x * 256;
    const int kz   = blockIdx.z * klen;

    // ds_read core offset: frag at tile-row base R -> R*64 + xo[kk],
    // xo[kk] = l15*64 + ((kk*4+l4)^(l15&7))*8  (slot-XOR swizzle)
    int xo[2];
    #pragma unroll
    for (int kk = 0; kk < 2; ++kk)
        xo[kk] = l15 * 64 + (((kk * 4 + l4) ^ (l15 & 7)) * 8);

    // staging core: lane covers row (lane>>3) of its 8-row block, LDS slot
    // lane&7; global chunk pre-swizzled (lane&7)^(row&7), row&7 == lane>>3.
    const size_t lsrc = (size_t)(lane >> 3) * lda + (((lane & 7) ^ (lane >> 3)) * 8);
    const unsigned short* Ag = A  + (size_t)m0 * lda + kz + lsrc;
    const unsigned short* Bg = Bw + (size_t)n0 * lda + kz + lsrc;

    f32x4 acc[8][4];
    #pragma unroll
    for (int mi = 0; mi < 8; ++mi)
        #pragma unroll
        for (int ni = 0; ni < 4; ++ni)
            acc[mi][ni] = (f32x4){0.f, 0.f, 0.f, 0.f};

    // stage unit: 0=A_lo 1=B_lo 2=B_hi 3=A_hi (16 KB each, 2 gll/thread)
    auto stage = [&](int tt, int unit) {
        const int buf = tt & 1;
        #pragma unroll
        for (int j = 0; j < 2; ++j) {
            const int u0 = wid * 16 + j * 8;       // 8-row block base
            int pr0;
            unsigned short* lb;
            const unsigned short* gs;
            if (unit == 0)      { pr0 = (u0 < 64) ? u0 : u0 + 64;         lb = Al[buf]; gs = Ag; }
            else if (unit == 3) { pr0 = (u0 < 64) ? u0 + 64 : u0 + 128;   lb = Al[buf]; gs = Ag; }
            else if (unit == 1) { pr0 = (u0 >> 5) * 64 + (u0 & 31);       lb = Bl[buf]; gs = Bg; }
            else                { pr0 = (u0 >> 5) * 64 + 32 + (u0 & 31);  lb = Bl[buf]; gs = Bg; }
            gll16(gs + (size_t)pr0 * lda + tt * 64, lb + pr0 * 64);
        }
    };

    const int NT = klen >> 6;
    // prologue: tile 0 fully staged; wait units 0,1 (allow 2,3 in flight)
    stage(0, 0); stage(0, 1); stage(0, 2); stage(0, 3);
    SBAR0();
    asm volatile("s_waitcnt vmcnt(4)" ::: "memory");
    SBAR0();
    __builtin_amdgcn_s_barrier();

    bf16x8 af[4][2], bfr[2][2], bflo[2][2];
    for (int t = 0; t < NT; ++t) {
        const unsigned short* Ab = Al[t & 1];
        const unsigned short* Bb = Bl[t & 1];
        const bool pf = (t + 1 < NT);

        // ---------------- P1: Q(lo,lo) — reads A_lo + B_lo (B_lo kept in regs)
        #pragma unroll
        for (int i = 0; i < 4; ++i)
            #pragma unroll
            for (int kk = 0; kk < 2; ++kk)
                af[i][kk] = *reinterpret_cast<const bf16x8*>(&Ab[(wrb + i * 16) * 64 + xo[kk]]);
        #pragma unroll
        for (int n = 0; n < 2; ++n)
            #pragma unroll
            for (int kk = 0; kk < 2; ++kk)
                bflo[n][kk] = *reinterpret_cast<const bf16x8*>(&Bb[(wcb + n * 16) * 64 + xo[kk]]);
        if (pf) stage(t + 1, 0);
        SBAR0();
        __builtin_amdgcn_s_barrier();          // overlaps ds_read latency
        asm volatile("s_waitcnt lgkmcnt(0)" ::: "memory");
        SBAR0();
        __builtin_amdgcn_s_setprio(1);
        #pragma unroll
        for (int kk = 0; kk < 2; ++kk)
            #pragma unroll
            for (int i = 0; i < 4; ++i)
                #pragma unroll
                for (int n = 0; n < 2; ++n)
                    acc[i][n] = __builtin_amdgcn_mfma_f32_16x16x32_bf16(af[i][kk], bflo[n][kk], acc[i][n], 0, 0, 0);
        __builtin_amdgcn_s_setprio(0);
        SBAR0();
        if (pf) asm volatile("s_waitcnt vmcnt(4)" ::: "memory");   // B_hi(t) landed
        else    asm volatile("s_waitcnt vmcnt(2)" ::: "memory");
        SBAR0();
        __builtin_amdgcn_s_barrier();

        // ---------------- P2: Q(lo,hi) — reads B_hi (A_lo regs live)
        #pragma unroll
        for (int n = 0; n < 2; ++n)
            #pragma unroll
            for (int kk = 0; kk < 2; ++kk)
                bfr[n][kk] = *reinterpret_cast<const bf16x8*>(&Bb[(wcb + 32 + n * 16) * 64 + xo[kk]]);
        if (pf) stage(t + 1, 1);
        SBAR0();
        __builtin_amdgcn_s_barrier();
        asm volatile("s_waitcnt lgkmcnt(0)" ::: "memory");
        SBAR0();
        __builtin_amdgcn_s_setprio(1);
        #pragma unroll
        for (int kk = 0; kk < 2; ++kk)
            #pragma unroll
            for (int i = 0; i < 4; ++i)
                #pragma unroll
                for (int n = 0; n < 2; ++n)
                    acc[i][2 + n] = __builtin_amdgcn_mfma_f32_16x16x32_bf16(af[i][kk], bfr[n][kk], acc[i][2 + n], 0, 0, 0);
        __builtin_amdgcn_s_setprio(0);
        SBAR0();
        if (pf) asm volatile("s_waitcnt vmcnt(4)" ::: "memory");   // A_hi(t) landed
        else    asm volatile("s_waitcnt vmcnt(0)" ::: "memory");
        SBAR0();
        __builtin_amdgcn_s_barrier();

        // ---------------- P3: Q(hi,hi) — reads A_hi (B_hi regs live)
        #pragma unroll
        for (int i = 0; i < 4; ++i)
            #pragma unroll
            for (int kk = 0; kk < 2; ++kk)
                af[i][kk] = *reinterpret_cast<const bf16x8*>(&Ab[(wrb + 64 + i * 16) * 64 + xo[kk]]);
        if (pf) stage(t + 1, 2);
        SBAR0();
        __builtin_amdgcn_s_barrier();
        asm volatile("s_waitcnt lgkmcnt(0)" ::: "memory");
        SBAR0();
        __builtin_amdgcn_s_setprio(1);
        #pragma unroll
        for (int kk = 0; kk < 2; ++kk)
            #pragma unroll
            for (int i = 0; i < 4; ++i)
                #pragma unroll
                for (int n = 0; n < 2; ++n)
                    acc[4 + i][2 + n] = __builtin_amdgcn_mfma_f32_16x16x32_bf16(af[i][kk], bfr[n][kk], acc[4 + i][2 + n], 0, 0, 0);
        __builtin_amdgcn_s_setprio(0);
        SBAR0();
        __builtin_amdgcn_s_barrier();                              // no vmcnt

        // ---------------- P4: Q(hi,lo) — B_lo from regs, no LDS reads
        if (pf) stage(t + 1, 3);
        SBAR0();
        __builtin_amdgcn_s_barrier();
        __builtin_amdgcn_s_setprio(1);
        #pragma unroll
        for (int kk = 0; kk < 2; ++kk)
            #pragma unroll
            for (int i = 0; i < 4; ++i)
                #pragma unroll
                for (int n = 0; n < 2; ++n)
                    acc[4 + i][n] = __builtin_amdgcn_mfma_f32_16x16x32_bf16(af[i][kk], bflo[n][kk], acc[4 + i][n], 0, 0, 0);
        __builtin_amdgcn_s_setprio(0);
        SBAR0();
        if (pf) asm volatile("s_waitcnt vmcnt(4)" ::: "memory");   // A_lo+B_lo(t+1)
        SBAR0();
        __builtin_amdgcn_s_barrier();
    }

    // epilogue: C/D layout col = lane&15, row = (lane>>4)*4 + r
    float* po = (blockIdx.z == 0) ? outf0 : outf1;
    #pragma unroll
    for (int h = 0; h < 2; ++h) {
        #pragma unroll
        for (int i = 0; i < 4; ++i) {
            #pragma unroll
            for (int ni = 0; ni < 4; ++ni) {
                const int col = n0 + wcb + ni * 16 + l15;
                const float bs = (mode == 3) ? 0.f : bias[col];
                #pragma unroll
                for (int r = 0; r < 4; ++r) {
                    const int row = m0 + wrb + h * 64 + i * 16 + l4 * 4 + r;
                    const float val = acc[h * 4 + i][ni][r] + bs;
                    if (mode == 0)      outb[(size_t)row * N + col] = f2bf(val);
                    else if (mode == 1) outb[(size_t)row * N + col] = f2bf(fmaxf(val, 0.f));
                    else                po[(size_t)row * N + col] = val;
                }
            }
        }
    }
}

// ---------------------------------------------------------------------------
// gemm_bt64: 64x128 tile, BK=32, 2-phase dbuf, for N=1024 GEMMs (grid 512 ->
// 2 blocks/CU). mode 0: bf16(acc+bias)   mode 2: f32 acc+bias+resid
// ---------------------------------------------------------------------------
__global__ __launch_bounds__(256) void gemm_bt64(
    const unsigned short* __restrict__ A,
    const unsigned short* __restrict__ Bw,
    const float* __restrict__ bias,
    const float* __restrict__ resid,
    unsigned short* __restrict__ outb,
    float* __restrict__ outf,
    int M, int N, int K, int mode)
{
    __shared__ unsigned short Al[2][64 * 32];
    __shared__ unsigned short Bl[2][128 * 32];
    const int tid  = threadIdx.x;
    const int lane = tid & 63;
    const int w    = tid >> 6;
    const int wr   = (w >> 1) * 32;
    const int wc   = (w & 1) * 64;
    const int l15  = lane & 15;
    const int l4   = lane >> 4;

    const int gx = gridDim.x;
    const int orig = blockIdx.y * gx + blockIdx.x;
    const int xcd  = orig & 7;
    const int lin  = orig >> 3;
    const int m0   = (xcd * 8 + (lin & 7)) * 64;
    const int n0   = (lin >> 3) * 128;

    const int srow = w * 16 + (lane >> 2);
    const int scol = ((lane & 3) ^ ((srow >> 1) & 3)) * 8;
    const unsigned short* ag = A  + (size_t)(m0 + srow) * K + scol;
    const unsigned short* bg = Bw + (size_t)(n0 + srow) * K + scol;
    const size_t jstep = (size_t)64 * K;
    const int lbase = (w * 16) * 32;

    int aoff[2], boff[4];
    #pragma unroll
    for (int i = 0; i < 2; ++i) {
        const int ra = wr + i * 16 + l15;
        aoff[i] = ra * 32 + ((l4 ^ ((ra >> 1) & 3)) * 8);
    }
    #pragma unroll
    for (int i = 0; i < 4; ++i) {
        const int rb = wc + i * 16 + l15;
        boff[i] = rb * 32 + ((l4 ^ ((rb >> 1) & 3)) * 8);
    }

    f32x4 acc[2][4];
    #pragma unroll
    for (int mi = 0; mi < 2; ++mi)
        #pragma unroll
        for (int ni = 0; ni < 4; ++ni)
            acc[mi][ni] = (f32x4){0.f, 0.f, 0.f, 0.f};

    gll16(ag, &Al[0][lbase]);
    #pragma unroll
    for (int j = 0; j < 2; ++j) gll16(bg + j * jstep, &Bl[0][lbase + j * 64 * 32]);
    __syncthreads();

    const int nt = K >> 5;
    int cur = 0;
    for (int t = 0; t < nt; ++t) {
        if (t + 1 < nt) {
            ag += 32; bg += 32;
            gll16(ag, &Al[cur ^ 1][lbase]);
            #pragma unroll
            for (int j = 0; j < 2; ++j) gll16(bg + j * jstep, &Bl[cur ^ 1][lbase + j * 64 * 32]);
        }
        const unsigned short* ac = &Al[cur][0];
        const unsigned short* bc = &Bl[cur][0];
        bf16x8 af[2], bf[4];
        #pragma unroll
        for (int i = 0; i < 2; ++i) af[i] = *reinterpret_cast<const bf16x8*>(&ac[aoff[i]]);
        #pragma unroll
        for (int i = 0; i < 4; ++i) bf[i] = *reinterpret_cast<const bf16x8*>(&bc[boff[i]]);
        #pragma unroll
        for (int mi = 0; mi < 2; ++mi)
            #pragma unroll
            for (int ni = 0; ni < 4; ++ni)
                acc[mi][ni] = __builtin_amdgcn_mfma_f32_16x16x32_bf16(af[mi], bf[ni], acc[mi][ni], 0, 0, 0);
        __syncthreads();
        cur ^= 1;
    }

    #pragma unroll
    for (int mi = 0; mi < 2; ++mi) {
        #pragma unroll
        for (int ni = 0; ni < 4; ++ni) {
            const int col = n0 + wc + ni * 16 + l15;
            const float bs = bias[col];
            #pragma unroll
            for (int r = 0; r < 4; ++r) {
                const int row = m0 + wr + mi * 16 + l4 * 4 + r;
                const float val = acc[mi][ni][r] + bs;
                if (mode == 0) outb[(size_t)row * N + col] = f2bf(val);
                else           outf[(size_t)row * N + col] = val + resid[(size_t)row * N + col];
            }
        }
    }
}

// ---------------------------------------------------------------------------
// Fused attention: one workgroup per (n,h). T=S=256, hd=64.
// ---------------------------------------------------------------------------
__global__ __launch_bounds__(256) void attn_fused(
    const unsigned short* __restrict__ Q, int qs,
    const unsigned short* __restrict__ Kb, int ks_,
    const unsigned short* __restrict__ Vb, int vs,
    unsigned short* __restrict__ O,
    int causal)
{
    __shared__ unsigned short Kl[8][256][8];
    __shared__ unsigned short Vt[32][64][8];
    __shared__ unsigned short Pl[4][32][16][8];
    const int tid  = threadIdx.x;
    const int lane = tid & 63;
    const int w    = tid >> 6;
    const int n    = blockIdx.x >> 4;
    const int h    = blockIdx.x & 15;
    const int l15  = lane & 15;
    const int l4   = lane >> 4;
    const size_t hoff = (size_t)h * 64;

    #pragma unroll
    for (int i = 0; i < 8; ++i) {
        const int e = i * 256 + tid;
        const int s = e >> 3;
        const int c = e & 7;
        u32x4 kv = *reinterpret_cast<const u32x4*>(&Kb[((size_t)s * 16 + n) * ks_ + hoff + c * 8]);
        *reinterpret_cast<u32x4*>(&Kl[c][s][0]) = kv;
        u32x4 vv = *reinterpret_cast<const u32x4*>(&Vb[((size_t)s * 16 + n) * vs + hoff + c * 8]);
        const unsigned short* ve = reinterpret_cast<const unsigned short*>(&vv);
        #pragma unroll
        for (int j = 0; j < 8; ++j)
            Vt[s >> 3][c * 8 + j][s & 7] = ve[j];
    }
    __syncthreads();

    for (int ch = 0; ch < 4; ++ch) {
        const int t0 = w * 64 + ch * 16;
        bf16x8 qa[2];
        #pragma unroll
        for (int ks = 0; ks < 2; ++ks)
            qa[ks] = *reinterpret_cast<const bf16x8*>(
                &Q[((size_t)(t0 + l15) * 16 + n) * qs + hoff + ks * 32 + l4 * 8]);

        f32x4 sc[16];
        #pragma unroll
        for (int st = 0; st < 16; ++st) {
            f32x4 a = (f32x4){0.f, 0.f, 0.f, 0.f};
            #pragma unroll
            for (int ks = 0; ks < 2; ++ks) {
                bf16x8 kf = *reinterpret_cast<const bf16x8*>(&Kl[ks * 4 + l4][st * 16 + l15][0]);
                a = __builtin_amdgcn_mfma_f32_16x16x32_bf16(qa[ks], kf, a, 0, 0, 0);
            }
            sc[st] = a;
        }
        if (causal) {
            #pragma unroll
            for (int st = 0; st < 16; ++st) {
                const int sg = st * 16 + l15;
                #pragma unroll
                for (int r = 0; r < 4; ++r) {
                    const int tg = t0 + l4 * 4 + r;
                    if (sg > tg) sc[st][r] += -1e9f;
                }
            }
        }
        #pragma unroll
        for (int r = 0; r < 4; ++r) {
            float mx = -3.0e38f;
            #pragma unroll
            for (int st = 0; st < 16; ++st) mx = fmaxf(mx, sc[st][r]);
            #pragma unroll
            for (int dd = 1; dd < 16; dd <<= 1) mx = fmaxf(mx, __shfl_xor(mx, dd, 64));
            float sum = 0.f;
            #pragma unroll
            for (int st = 0; st < 16; ++st) {
                const float e = __expf(sc[st][r] - mx);
                sc[st][r] = e;
                sum += e;
            }
            #pragma unroll
            for (int dd = 1; dd < 16; dd <<= 1) sum += __shfl_xor(sum, dd, 64);
            const float inv = 1.f / sum;
            const int rl = l4 * 4 + r;
            #pragma unroll
            for (int st = 0; st < 16; ++st) {
                const int sg = st * 16 + l15;
                Pl[w][sg >> 3][rl][sg & 7] = f2bf(sc[st][r] * inv);
            }
        }
        f32x4 oacc[4];
        #pragma unroll
        for (int dt = 0; dt < 4; ++dt) oacc[dt] = (f32x4){0.f, 0.f, 0.f, 0.f};
        #pragma unroll
        for (int kt = 0; kt < 8; ++kt) {
            bf16x8 pa = *reinterpret_cast<const bf16x8*>(&Pl[w][kt * 4 + l4][l15][0]);
            #pragma unroll
            for (int dt = 0; dt < 4; ++dt) {
                bf16x8 vf = *reinterpret_cast<const bf16x8*>(&Vt[kt * 4 + l4][dt * 16 + l15][0]);
                oacc[dt] = __builtin_amdgcn_mfma_f32_16x16x32_bf16(pa, vf, oacc[dt], 0, 0, 0);
            }
        }
        #pragma unroll
        for (int dt = 0; dt < 4; ++dt)
            #pragma unroll
            for (int r = 0; r < 4; ++r)
                O[((size_t)(t0 + l4 * 4 + r) * 16 + n) * 1024 + hoff + dt * 16 + l15] = f2bf(oacc[dt][r]);
    }
}

// ---------------------------------------------------------------------------
// LayerNorm over D=1024, one wave per row (plain and fused-reduce variants)
// ---------------------------------------------------------------------------
__device__ __forceinline__ void ln_body(
    f32x4 (&v)[4], int row, int lane,
    const float* __restrict__ g, const float* __restrict__ b,
    float* __restrict__ xf, unsigned short* __restrict__ xb)
{
    float s = 0.f;
    #pragma unroll
    for (int i = 0; i < 4; ++i) s += v[i][0] + v[i][1] + v[i][2] + v[i][3];
    #pragma unroll
    for (int dd = 1; dd < 64; dd <<= 1) s += __shfl_xor(s, dd, 64);
    const float mu = s * (1.f / 1024.f);
    float q = 0.f;
    #pragma unroll
    for (int i = 0; i < 4; ++i)
        #pragma unroll
        for (int j = 0; j < 4; ++j) { const float d0 = v[i][j] - mu; q += d0 * d0; }
    #pragma unroll
    for (int dd = 1; dd < 64; dd <<= 1) q += __shfl_xor(q, dd, 64);
    const float rstd = rsqrtf(q * (1.f / 1024.f) + 1e-5f);
    #pragma unroll
    for (int i = 0; i < 4; ++i) {
        const int col = i * 256 + lane * 4;
        f32x4 gg = *reinterpret_cast<const f32x4*>(&g[col]);
        f32x4 bb = *reinterpret_cast<const f32x4*>(&b[col]);
        f32x4 y;
        #pragma unroll
        for (int j = 0; j < 4; ++j) y[j] = (v[i][j] - mu) * rstd * gg[j] + bb[j];
        if (xf) *reinterpret_cast<f32x4*>(&xf[(size_t)row * 1024 + col]) = y;
        if (xb) {
            u16x4 pk;
            #pragma unroll
            for (int j = 0; j < 4; ++j) pk[j] = f2bf(y[j]);
            *reinterpret_cast<u16x4*>(&xb[(size_t)row * 1024 + col]) = pk;
        }
    }
}

__global__ __launch_bounds__(256) void ln_kernel(
    const float* __restrict__ z, const float* __restrict__ g, const float* __restrict__ b,
    float* __restrict__ xf, unsigned short* __restrict__ xb)
{
    const int row  = blockIdx.x * 4 + (threadIdx.x >> 6);
    const int lane = threadIdx.x & 63;
    f32x4 v[4];
    #pragma unroll
    for (int i = 0; i < 4; ++i)
        v[i] = *reinterpret_cast<const f32x4*>(&z[(size_t)row * 1024 + i * 256 + lane * 4]);
    ln_body(v, row, lane, g, b, xf, xb);
}

__global__ __launch_bounds__(256) void ln_red2(
    const float* __restrict__ p0, const float* __restrict__ p1,
    const float* __restrict__ bias, const float* __restrict__ resid,
    const float* __restrict__ g, const float* __restrict__ b,
    float* __restrict__ xf, unsigned short* __restrict__ xb)
{
    const int row  = blockIdx.x * 4 + (threadIdx.x >> 6);
    const int lane = threadIdx.x & 63;
    f32x4 v[4];
    #pragma unroll
    for (int i = 0; i < 4; ++i) {
        const int col = i * 256 + lane * 4;
        const size_t o = (size_t)row * 1024 + col;
        f32x4 a0 = *reinterpret_cast<const f32x4*>(&p0[o]);
        f32x4 a1 = *reinterpret_cast<const f32x4*>(&p1[o]);
        f32x4 bs = *reinterpret_cast<const f32x4*>(&bias[col]);
        f32x4 rs = *reinterpret_cast<const f32x4*>(&resid[o]);
        v[i] = a0 + a1 + bs + rs;
    }
    ln_body(v, row, lane, g, b, xf, xb);
}

__global__ __launch_bounds__(256) void cvt_bf16(
    const float* __restrict__ in, unsigned short* __restrict__ out, int n)
{
    const int i = (blockIdx.x * 256 + threadIdx.x) * 4;
    if (i >= n) return;
    f32x4 v = *reinterpret_cast<const f32x4*>(&in[i]);
    u16x4 pk;
    #pragma unroll
    for (int j = 0; j < 4; ++j) pk[j] = f2bf(v[j]);
    *reinterpret_cast<u16x4*>(&out[i]) = pk;
}

// ---------------------------------------------------------------------------
// Per-layer weight pack (fp32->bf16, Q-scale folded):
//   [0,3DD) sa qkv  [3DD,6DD) ca qkv  [6DD,7DD) sa_wo  [7DD,8DD) ca_wo
//   [8DD,12DD) w1   [12DD,16DD) w2
// ---------------------------------------------------------------------------
__global__ __launch_bounds__(256) void pack_layer_w(
    const float* __restrict__ sa_wq, const float* __restrict__ sa_wk, const float* __restrict__ sa_wv,
    const float* __restrict__ ca_wq, const float* __restrict__ ca_wk, const float* __restrict__ ca_wv,
    const float* __restrict__ sa_wo, const float* __restrict__ ca_wo,
    const float* __restrict__ w1,   const float* __restrict__ w2,
    unsigned short* __restrict__ dst, int layer)
{
    const size_t DD = 1024u * 1024u;
    const size_t e  = ((size_t)blockIdx.x * 256 + threadIdx.x) * 4;
    const float* src;
    float scale = 1.f;
    if (e < 3 * DD) {
        const int part = (int)(e / DD);
        src = (part == 0 ? sa_wq : part == 1 ? sa_wk : sa_wv) + layer * DD + (e % DD);
        if (part == 0) scale = 0.125f;
    } else if (e < 6 * DD) {
        const size_t r = e - 3 * DD;
        const int part = (int)(r / DD);
        src = (part == 0 ? ca_wq : part == 1 ? ca_wk : ca_wv) + layer * DD + (r % DD);
        if (part == 0) scale = 0.125f;
    } else if (e < 7 * DD)  { src = sa_wo + layer * DD + (e - 6 * DD); }
    else if (e < 8 * DD)    { src = ca_wo + layer * DD + (e - 7 * DD); }
    else if (e < 12 * DD)   { src = w1 + (size_t)layer * 4 * DD + (e - 8 * DD); }
    else                    { src = w2 + (size_t)layer * 4 * DD + (e - 12 * DD); }
    f32x4 v = *reinterpret_cast<const f32x4*>(src);
    u16x4 pk;
    #pragma unroll
    for (int j = 0; j < 4; ++j) pk[j] = f2bf(v[j] * scale);
    *reinterpret_cast<u16x4*>(&dst[e]) = pk;
}

__global__ __launch_bounds__(256) void pack_bias(
    const float* __restrict__ sa_bq, const float* __restrict__ sa_bk, const float* __restrict__ sa_bv,
    const float* __restrict__ ca_bq, const float* __restrict__ ca_bk, const float* __restrict__ ca_bv,
    float* __restrict__ sab, float* __restrict__ cab)
{
    const int idx = blockIdx.x * 256 + threadIdx.x;
    const int half = idx / 12288;
    const int r    = idx % 12288;
    const int l    = r / 3072;
    const int pc   = r % 3072;
    const int part = pc >> 10;
    const int c    = pc & 1023;
    const float* src = half == 0 ? (part == 0 ? sa_bq : part == 1 ? sa_bk : sa_bv)
                                 : (part == 0 ? ca_bq : part == 1 ? ca_bk : ca_bv);
    const float v = src[l * 1024 + c] * (part == 0 ? 0.125f : 1.f);
    (half ? cab : sab)[l * 3072 + pc] = v;
}

// ---------------------------------------------------------------------------
extern "C" void kernel_launch(void* const* d_in, const int* in_sizes, int n_in,
                              void* d_out, int out_size, void* d_ws, size_t ws_size,
                              hipStream_t stream)
{
    (void)in_sizes; (void)n_in; (void)out_size; (void)ws_size;
    const int M  = 4096;
    const int Dm = 1024;
    const size_t DD = (size_t)Dm * Dm;

    const float* tgt   = (const float*)d_in[0];
    const float* mem   = (const float*)d_in[1];
    const float* sa_wq = (const float*)d_in[2];
    const float* sa_wk = (const float*)d_in[3];
    const float* sa_wv = (const float*)d_in[4];
    const float* sa_wo = (const float*)d_in[5];
    const float* sa_bq = (const float*)d_in[6];
    const float* sa_bk = (const float*)d_in[7];
    const float* sa_bv = (const float*)d_in[8];
    const float* sa_bo = (const float*)d_in[9];
    const float* ca_wq = (const float*)d_in[10];
    const float* ca_wk = (const float*)d_in[11];
    const float* ca_wv = (const float*)d_in[12];
    const float* ca_wo = (const float*)d_in[13];
    const float* ca_bq = (const float*)d_in[14];
    const float* ca_bk = (const float*)d_in[15];
    const float* ca_bv = (const float*)d_in[16];
    const float* ca_bo = (const float*)d_in[17];
    const float* w1    = (const float*)d_in[18];
    const float* b1    = (const float*)d_in[19];
    const float* w2    = (const float*)d_in[20];
    const float* b2    = (const float*)d_in[21];
    const float* ln1g  = (const float*)d_in[22];
    const float* ln1b  = (const float*)d_in[23];
    const float* ln2g  = (const float*)d_in[24];
    const float* ln2b  = (const float*)d_in[25];
    const float* ln3g  = (const float*)d_in[26];
    const float* ln3b  = (const float*)d_in[27];
    const float* lnfg  = (const float*)d_in[28];
    const float* lnfb  = (const float*)d_in[29];

    char* p = (char*)d_ws;
    float*          x_f    = (float*)p;          p += (size_t)M * Dm * 4;
    unsigned short* x_b    = (unsigned short*)p; p += (size_t)M * Dm * 2;
    unsigned short* mem_b  = (unsigned short*)p; p += (size_t)M * Dm * 2;
    unsigned short* qkv_b  = (unsigned short*)p; p += (size_t)M * 3072 * 2;
    unsigned short* cakv_b = (unsigned short*)p; p += (size_t)M * 2048 * 2;
    unsigned short* caq_b  = (unsigned short*)p; p += (size_t)M * Dm * 2;
    unsigned short* ao_b   = (unsigned short*)p; p += (size_t)M * Dm * 2;
    unsigned short* wpack  = (unsigned short*)p; p += 16 * DD * 2;
    float*          sab    = (float*)p;          p += 4 * 3072 * 4;
    float*          cab    = (float*)p;          p += 4 * 3072 * 4;
    unsigned short* h_b    = qkv_b;                                          // [4096][4096] bf16
    float*          par0   = (float*)((char*)qkv_b + (size_t)M * 4096 * 2);  // dead cakv tail+caq+ao
    float*          par1   = (float*)wpack;                                  // dead packed weights
    float*          z_f    = (float*)d_out;

    dim3 blk(256), blk5(512);
    auto gemm64 = [&](const unsigned short* A, const unsigned short* Bw, const float* bias,
                      const float* resid, unsigned short* ob, float* of, int N, int K, int mode) {
        dim3 grid(N / 128, M / 64);
        gemm_bt64<<<grid, blk, 0, stream>>>(A, Bw, bias, resid, ob, of, M, N, K, mode);
    };

    cvt_bf16<<<4096, blk, 0, stream>>>(tgt, x_b, M * Dm);
    cvt_bf16<<<4096, blk, 0, stream>>>(mem, mem_b, M * Dm);
    pack_bias<<<96, blk, 0, stream>>>(sa_bq, sa_bk, sa_bv, ca_bq, ca_bk, ca_bv, sab, cab);

    const float* res = tgt;
    for (int i = 0; i < 4; ++i) {
        pack_layer_w<<<16384, blk, 0, stream>>>(sa_wq, sa_wk, sa_wv, ca_wq, ca_wk, ca_wv,
                                                sa_wo, ca_wo, w1, w2, wpack, i);
        // --- self-attention (fused QKV, N=3072) ---
        gemm256<<<dim3(12, 16, 1), blk5, 0, stream>>>(x_b, wpack, sab + i * 3072,
            qkv_b, nullptr, nullptr, 3072, 1024, 1024, 0);
        attn_fused<<<256, blk, 0, stream>>>(qkv_b, 3072, qkv_b + 1024, 3072, qkv_b + 2048, 3072, ao_b, 1);
        gemm64(ao_b, wpack + 6 * DD, sa_bo + i * Dm, res, nullptr, z_f, 1024, 1024, 2);
        ln_kernel<<<1024, blk, 0, stream>>>(z_f, ln1g + i * Dm, ln1b + i * Dm, x_f, x_b);
        res = x_f;
        // --- cross-attention (Q from x; fused KV from memory, N=2048) ---
        gemm64(x_b, wpack + 3 * DD, cab + i * 3072, nullptr, caq_b, nullptr, 1024, 1024, 0);
        gemm256<<<dim3(8, 16, 1), blk5, 0, stream>>>(mem_b, wpack + 4 * DD, cab + i * 3072 + 1024,
            cakv_b, nullptr, nullptr, 2048, 1024, 1024, 0);
        attn_fused<<<256, blk, 0, stream>>>(caq_b, 1024, cakv_b, 2048, cakv_b + 1024, 2048, ao_b, 0);
        gemm64(ao_b, wpack + 7 * DD, ca_bo + i * Dm, x_f, nullptr, z_f, 1024, 1024, 2);
        ln_kernel<<<1024, blk, 0, stream>>>(z_f, ln2g + i * Dm, ln2b + i * Dm, x_f, x_b);
        // --- FFN ---
        gemm256<<<dim3(16, 16, 1), blk5, 0, stream>>>(x_b, wpack + 8 * DD, b1 + i * 4096,
            h_b, nullptr, nullptr, 4096, 1024, 1024, 1);
        gemm256<<<dim3(4, 16, 2), blk5, 0, stream>>>(h_b, wpack + 12 * DD, nullptr,
            nullptr, par0, par1, 1024, 4096, 2048, 3);
        ln_red2<<<1024, blk, 0, stream>>>(par0, par1, b2 + i * Dm, x_f,
            ln3g + i * Dm, ln3b + i * Dm, x_f, x_b);
    }
    ln_kernel<<<1024, blk, 0, stream>>>(x_f, lnfg, lnfb, (float*)d_out, nullptr);
}

// Round 7
// 1357.729 us; speedup vs baseline: 1.1210x; 1.1210x over previous
//
#include <hip/hip_runtime.h>

// ---------------------------------------------------------------------------
// 4-layer transformer decoder, bf16 MFMA implementation (round 7).
// All big GEMMs: gemm128 = 128x128 tile, BK=32, double-buffered 2-phase loop,
// 4 waves, 4 blocks/CU (TLP hides barrier drains; m97/m114 mechanism).
// Zero-conflict slot-XOR LDS swizzle + XCD band swizzle. N=1024 GEMMs on
// gemm_bt64 (2 blocks/CU). FFN2 = split-K2 + reduce fused into LN3.
// ---------------------------------------------------------------------------

typedef __attribute__((ext_vector_type(4))) float f32x4;
typedef __attribute__((ext_vector_type(8))) short bf16x8;
typedef __attribute__((ext_vector_type(4))) unsigned short u16x4;
typedef __attribute__((ext_vector_type(4))) unsigned int   u32x4;

__device__ __forceinline__ unsigned short f2bf(float f) {
    unsigned int u = __builtin_bit_cast(unsigned int, f);
    u += 0x7fffu + ((u >> 16) & 1u);   // RNE
    return (unsigned short)(u >> 16);
}

__device__ __forceinline__ void gll16(const unsigned short* g, unsigned short* l) {
    auto* gp = reinterpret_cast<const __attribute__((address_space(1))) unsigned int*>(
        reinterpret_cast<uintptr_t>(g));
    auto* lp = reinterpret_cast<__attribute__((address_space(3))) unsigned int*>(
        reinterpret_cast<uintptr_t>(l));
    __builtin_amdgcn_global_load_lds(gp, lp, 16, 0, 0);
}

// ---------------------------------------------------------------------------
// gemm128: out = epilogue( A(bf16)[M][lda] @ Bw(bf16)[N][lda]^T ), K range
// [kz, kz+klen), kz = blockIdx.z*klen. 128x128 tile, 4 waves (2x2), each
// 64x64 out. LDS 2 x (128x32) per operand = 32 KiB -> 4 blocks/CU.
// mode 0: bf16(acc+bias)  1: bf16(relu(acc+bias))  3: raw f32 -> outf{0,1}
// ---------------------------------------------------------------------------
__global__ __launch_bounds__(256, 4) void gemm128(
    const unsigned short* __restrict__ A,
    const unsigned short* __restrict__ Bw,
    const float* __restrict__ bias,
    unsigned short* __restrict__ outb,
    float* __restrict__ outf0,
    float* __restrict__ outf1,
    int N, int lda, int klen, int mode)
{
    __shared__ unsigned short Al[2][128 * 32];
    __shared__ unsigned short Bl[2][128 * 32];
    const int tid  = threadIdx.x;
    const int lane = tid & 63;
    const int w    = tid >> 6;
    const int wr   = (w >> 1) * 64;
    const int wc   = (w & 1) * 64;
    const int l15  = lane & 15;
    const int l4   = lane >> 4;

    // XCD band swizzle: gy == 32 always here -> each XCD owns a 4-row band,
    // traversed column-major (A panels L2-resident per XCD).
    const int gx   = gridDim.x;
    const int orig = blockIdx.y * gx + blockIdx.x;
    const int xcd  = orig & 7;
    const int lin  = orig >> 3;
    const int m0   = (xcd * 4 + (lin & 3)) * 128;
    const int n0   = (lin >> 2) * 128;
    const int kz   = blockIdx.z * klen;

    // staging: wave w covers rows w*16..w*16+15 (+64 for j=1); lane's 16B
    // chunk lands at LDS slot lane&3; global col pre-swizzled slot^((row>>1)&3).
    const int srow = w * 16 + (lane >> 2);
    const int scol = ((lane & 3) ^ ((srow >> 1) & 3)) * 8;
    const unsigned short* ag = A  + (size_t)(m0 + srow) * lda + kz + scol;
    const unsigned short* bg = Bw + (size_t)(n0 + srow) * lda + kz + scol;
    const size_t jstep = (size_t)64 * lda;
    const int lbase = (w * 16) * 32;

    // fragment read offsets: row r, k-chunk l4 at slot l4^((r>>1)&3)
    int aoff[4], boff[4];
    #pragma unroll
    for (int i = 0; i < 4; ++i) {
        const int ra = wr + i * 16 + l15;
        const int rb = wc + i * 16 + l15;
        aoff[i] = ra * 32 + ((l4 ^ ((ra >> 1) & 3)) * 8);
        boff[i] = rb * 32 + ((l4 ^ ((rb >> 1) & 3)) * 8);
    }

    f32x4 acc[4][4];
    #pragma unroll
    for (int mi = 0; mi < 4; ++mi)
        #pragma unroll
        for (int ni = 0; ni < 4; ++ni)
            acc[mi][ni] = (f32x4){0.f, 0.f, 0.f, 0.f};

    // prologue: stage tile 0 into buf 0
    #pragma unroll
    for (int j = 0; j < 2; ++j) {
        gll16(ag + j * jstep, &Al[0][lbase + j * 64 * 32]);
        gll16(bg + j * jstep, &Bl[0][lbase + j * 64 * 32]);
    }
    __syncthreads();

    const int nt = klen >> 5;
    int cur = 0;
    for (int t = 0; t < nt; ++t) {
        if (t + 1 < nt) {                      // issue next-tile loads first
            ag += 32; bg += 32;
            #pragma unroll
            for (int j = 0; j < 2; ++j) {
                gll16(ag + j * jstep, &Al[cur ^ 1][lbase + j * 64 * 32]);
                gll16(bg + j * jstep, &Bl[cur ^ 1][lbase + j * 64 * 32]);
            }
        }
        const unsigned short* ac = &Al[cur][0];
        const unsigned short* bc = &Bl[cur][0];
        bf16x8 af[4], bf[4];
        #pragma unroll
        for (int i = 0; i < 4; ++i) af[i] = *reinterpret_cast<const bf16x8*>(&ac[aoff[i]]);
        #pragma unroll
        for (int i = 0; i < 4; ++i) bf[i] = *reinterpret_cast<const bf16x8*>(&bc[boff[i]]);
        #pragma unroll
        for (int mi = 0; mi < 4; ++mi)
            #pragma unroll
            for (int ni = 0; ni < 4; ++ni)
                acc[mi][ni] = __builtin_amdgcn_mfma_f32_16x16x32_bf16(af[mi], bf[ni], acc[mi][ni], 0, 0, 0);
        __syncthreads();                       // drains vmcnt: next buf ready
        cur ^= 1;
    }

    // epilogue: C/D layout col = lane&15, row = (lane>>4)*4 + r
    float* po = (blockIdx.z == 0) ? outf0 : outf1;
    #pragma unroll
    for (int mi = 0; mi < 4; ++mi) {
        #pragma unroll
        for (int ni = 0; ni < 4; ++ni) {
            const int col = n0 + wc + ni * 16 + l15;
            const float bs = (mode == 3) ? 0.f : bias[col];
            #pragma unroll
            for (int r = 0; r < 4; ++r) {
                const int row = m0 + wr + mi * 16 + l4 * 4 + r;
                const float val = acc[mi][ni][r] + bs;
                if (mode == 0)      outb[(size_t)row * N + col] = f2bf(val);
                else if (mode == 1) outb[(size_t)row * N + col] = f2bf(fmaxf(val, 0.f));
                else                po[(size_t)row * N + col] = val;
            }
        }
    }
}

// ---------------------------------------------------------------------------
// gemm_bt64: 64x128 tile, BK=32, 2-phase dbuf, for N=1024 GEMMs (grid 512 ->
// 2 blocks/CU). mode 0: bf16(acc+bias)   mode 2: f32 acc+bias+resid
// ---------------------------------------------------------------------------
__global__ __launch_bounds__(256) void gemm_bt64(
    const unsigned short* __restrict__ A,
    const unsigned short* __restrict__ Bw,
    const float* __restrict__ bias,
    const float* __restrict__ resid,
    unsigned short* __restrict__ outb,
    float* __restrict__ outf,
    int M, int N, int K, int mode)
{
    __shared__ unsigned short Al[2][64 * 32];
    __shared__ unsigned short Bl[2][128 * 32];
    const int tid  = threadIdx.x;
    const int lane = tid & 63;
    const int w    = tid >> 6;
    const int wr   = (w >> 1) * 32;
    const int wc   = (w & 1) * 64;
    const int l15  = lane & 15;
    const int l4   = lane >> 4;

    const int gx = gridDim.x;
    const int orig = blockIdx.y * gx + blockIdx.x;
    const int xcd  = orig & 7;
    const int lin  = orig >> 3;
    const int m0   = (xcd * 8 + (lin & 7)) * 64;
    const int n0   = (lin >> 3) * 128;

    const int srow = w * 16 + (lane >> 2);
    const int scol = ((lane & 3) ^ ((srow >> 1) & 3)) * 8;
    const unsigned short* ag = A  + (size_t)(m0 + srow) * K + scol;
    const unsigned short* bg = Bw + (size_t)(n0 + srow) * K + scol;
    const size_t jstep = (size_t)64 * K;
    const int lbase = (w * 16) * 32;

    int aoff[2], boff[4];
    #pragma unroll
    for (int i = 0; i < 2; ++i) {
        const int ra = wr + i * 16 + l15;
        aoff[i] = ra * 32 + ((l4 ^ ((ra >> 1) & 3)) * 8);
    }
    #pragma unroll
    for (int i = 0; i < 4; ++i) {
        const int rb = wc + i * 16 + l15;
        boff[i] = rb * 32 + ((l4 ^ ((rb >> 1) & 3)) * 8);
    }

    f32x4 acc[2][4];
    #pragma unroll
    for (int mi = 0; mi < 2; ++mi)
        #pragma unroll
        for (int ni = 0; ni < 4; ++ni)
            acc[mi][ni] = (f32x4){0.f, 0.f, 0.f, 0.f};

    gll16(ag, &Al[0][lbase]);
    #pragma unroll
    for (int j = 0; j < 2; ++j) gll16(bg + j * jstep, &Bl[0][lbase + j * 64 * 32]);
    __syncthreads();

    const int nt = K >> 5;
    int cur = 0;
    for (int t = 0; t < nt; ++t) {
        if (t + 1 < nt) {
            ag += 32; bg += 32;
            gll16(ag, &Al[cur ^ 1][lbase]);
            #pragma unroll
            for (int j = 0; j < 2; ++j) gll16(bg + j * jstep, &Bl[cur ^ 1][lbase + j * 64 * 32]);
        }
        const unsigned short* ac = &Al[cur][0];
        const unsigned short* bc = &Bl[cur][0];
        bf16x8 af[2], bf[4];
        #pragma unroll
        for (int i = 0; i < 2; ++i) af[i] = *reinterpret_cast<const bf16x8*>(&ac[aoff[i]]);
        #pragma unroll
        for (int i = 0; i < 4; ++i) bf[i] = *reinterpret_cast<const bf16x8*>(&bc[boff[i]]);
        #pragma unroll
        for (int mi = 0; mi < 2; ++mi)
            #pragma unroll
            for (int ni = 0; ni < 4; ++ni)
                acc[mi][ni] = __builtin_amdgcn_mfma_f32_16x16x32_bf16(af[mi], bf[ni], acc[mi][ni], 0, 0, 0);
        __syncthreads();
        cur ^= 1;
    }

    #pragma unroll
    for (int mi = 0; mi < 2; ++mi) {
        #pragma unroll
        for (int ni = 0; ni < 4; ++ni) {
            const int col = n0 + wc + ni * 16 + l15;
            const float bs = bias[col];
            #pragma unroll
            for (int r = 0; r < 4; ++r) {
                const int row = m0 + wr + mi * 16 + l4 * 4 + r;
                const float val = acc[mi][ni][r] + bs;
                if (mode == 0) outb[(size_t)row * N + col] = f2bf(val);
                else           outf[(size_t)row * N + col] = val + resid[(size_t)row * N + col];
            }
        }
    }
}

// ---------------------------------------------------------------------------
// Fused attention: one workgroup per (n,h). T=S=256, hd=64.
// ---------------------------------------------------------------------------
__global__ __launch_bounds__(256) void attn_fused(
    const unsigned short* __restrict__ Q, int qs,
    const unsigned short* __restrict__ Kb, int ks_,
    const unsigned short* __restrict__ Vb, int vs,
    unsigned short* __restrict__ O,
    int causal)
{
    __shared__ unsigned short Kl[8][256][8];
    __shared__ unsigned short Vt[32][64][8];
    __shared__ unsigned short Pl[4][32][16][8];
    const int tid  = threadIdx.x;
    const int lane = tid & 63;
    const int w    = tid >> 6;
    const int n    = blockIdx.x >> 4;
    const int h    = blockIdx.x & 15;
    const int l15  = lane & 15;
    const int l4   = lane >> 4;
    const size_t hoff = (size_t)h * 64;

    #pragma unroll
    for (int i = 0; i < 8; ++i) {
        const int e = i * 256 + tid;
        const int s = e >> 3;
        const int c = e & 7;
        u32x4 kv = *reinterpret_cast<const u32x4*>(&Kb[((size_t)s * 16 + n) * ks_ + hoff + c * 8]);
        *reinterpret_cast<u32x4*>(&Kl[c][s][0]) = kv;
        u32x4 vv = *reinterpret_cast<const u32x4*>(&Vb[((size_t)s * 16 + n) * vs + hoff + c * 8]);
        const unsigned short* ve = reinterpret_cast<const unsigned short*>(&vv);
        #pragma unroll
        for (int j = 0; j < 8; ++j)
            Vt[s >> 3][c * 8 + j][s & 7] = ve[j];
    }
    __syncthreads();

    for (int ch = 0; ch < 4; ++ch) {
        const int t0 = w * 64 + ch * 16;
        bf16x8 qa[2];
        #pragma unroll
        for (int ks = 0; ks < 2; ++ks)
            qa[ks] = *reinterpret_cast<const bf16x8*>(
                &Q[((size_t)(t0 + l15) * 16 + n) * qs + hoff + ks * 32 + l4 * 8]);

        f32x4 sc[16];
        #pragma unroll
        for (int st = 0; st < 16; ++st) {
            f32x4 a = (f32x4){0.f, 0.f, 0.f, 0.f};
            #pragma unroll
            for (int ks = 0; ks < 2; ++ks) {
                bf16x8 kf = *reinterpret_cast<const bf16x8*>(&Kl[ks * 4 + l4][st * 16 + l15][0]);
                a = __builtin_amdgcn_mfma_f32_16x16x32_bf16(qa[ks], kf, a, 0, 0, 0);
            }
            sc[st] = a;
        }
        if (causal) {
            #pragma unroll
            for (int st = 0; st < 16; ++st) {
                const int sg = st * 16 + l15;
                #pragma unroll
                for (int r = 0; r < 4; ++r) {
                    const int tg = t0 + l4 * 4 + r;
                    if (sg > tg) sc[st][r] += -1e9f;
                }
            }
        }
        #pragma unroll
        for (int r = 0; r < 4; ++r) {
            float mx = -3.0e38f;
            #pragma unroll
            for (int st = 0; st < 16; ++st) mx = fmaxf(mx, sc[st][r]);
            #pragma unroll
            for (int dd = 1; dd < 16; dd <<= 1) mx = fmaxf(mx, __shfl_xor(mx, dd, 64));
            float sum = 0.f;
            #pragma unroll
            for (int st = 0; st < 16; ++st) {
                const float e = __expf(sc[st][r] - mx);
                sc[st][r] = e;
                sum += e;
            }
            #pragma unroll
            for (int dd = 1; dd < 16; dd <<= 1) sum += __shfl_xor(sum, dd, 64);
            const float inv = 1.f / sum;
            const int rl = l4 * 4 + r;
            #pragma unroll
            for (int st = 0; st < 16; ++st) {
                const int sg = st * 16 + l15;
                Pl[w][sg >> 3][rl][sg & 7] = f2bf(sc[st][r] * inv);
            }
        }
        f32x4 oacc[4];
        #pragma unroll
        for (int dt = 0; dt < 4; ++dt) oacc[dt] = (f32x4){0.f, 0.f, 0.f, 0.f};
        #pragma unroll
        for (int kt = 0; kt < 8; ++kt) {
            bf16x8 pa = *reinterpret_cast<const bf16x8*>(&Pl[w][kt * 4 + l4][l15][0]);
            #pragma unroll
            for (int dt = 0; dt < 4; ++dt) {
                bf16x8 vf = *reinterpret_cast<const bf16x8*>(&Vt[kt * 4 + l4][dt * 16 + l15][0]);
                oacc[dt] = __builtin_amdgcn_mfma_f32_16x16x32_bf16(pa, vf, oacc[dt], 0, 0, 0);
            }
        }
        #pragma unroll
        for (int dt = 0; dt < 4; ++dt)
            #pragma unroll
            for (int r = 0; r < 4; ++r)
                O[((size_t)(t0 + l4 * 4 + r) * 16 + n) * 1024 + hoff + dt * 16 + l15] = f2bf(oacc[dt][r]);
    }
}

// ---------------------------------------------------------------------------
// LayerNorm over D=1024, one wave per row (plain and fused-reduce variants)
// ---------------------------------------------------------------------------
__device__ __forceinline__ void ln_body(
    f32x4 (&v)[4], int row, int lane,
    const float* __restrict__ g, const float* __restrict__ b,
    float* __restrict__ xf, unsigned short* __restrict__ xb)
{
    float s = 0.f;
    #pragma unroll
    for (int i = 0; i < 4; ++i) s += v[i][0] + v[i][1] + v[i][2] + v[i][3];
    #pragma unroll
    for (int dd = 1; dd < 64; dd <<= 1) s += __shfl_xor(s, dd, 64);
    const float mu = s * (1.f / 1024.f);
    float q = 0.f;
    #pragma unroll
    for (int i = 0; i < 4; ++i)
        #pragma unroll
        for (int j = 0; j < 4; ++j) { const float d0 = v[i][j] - mu; q += d0 * d0; }
    #pragma unroll
    for (int dd = 1; dd < 64; dd <<= 1) q += __shfl_xor(q, dd, 64);
    const float rstd = rsqrtf(q * (1.f / 1024.f) + 1e-5f);
    #pragma unroll
    for (int i = 0; i < 4; ++i) {
        const int col = i * 256 + lane * 4;
        f32x4 gg = *reinterpret_cast<const f32x4*>(&g[col]);
        f32x4 bb = *reinterpret_cast<const f32x4*>(&b[col]);
        f32x4 y;
        #pragma unroll
        for (int j = 0; j < 4; ++j) y[j] = (v[i][j] - mu) * rstd * gg[j] + bb[j];
        if (xf) *reinterpret_cast<f32x4*>(&xf[(size_t)row * 1024 + col]) = y;
        if (xb) {
            u16x4 pk;
            #pragma unroll
            for (int j = 0; j < 4; ++j) pk[j] = f2bf(y[j]);
            *reinterpret_cast<u16x4*>(&xb[(size_t)row * 1024 + col]) = pk;
        }
    }
}

__global__ __launch_bounds__(256) void ln_kernel(
    const float* __restrict__ z, const float* __restrict__ g, const float* __restrict__ b,
    float* __restrict__ xf, unsigned short* __restrict__ xb)
{
    const int row  = blockIdx.x * 4 + (threadIdx.x >> 6);
    const int lane = threadIdx.x & 63;
    f32x4 v[4];
    #pragma unroll
    for (int i = 0; i < 4; ++i)
        v[i] = *reinterpret_cast<const f32x4*>(&z[(size_t)row * 1024 + i * 256 + lane * 4]);
    ln_body(v, row, lane, g, b, xf, xb);
}

__global__ __launch_bounds__(256) void ln_red2(
    const float* __restrict__ p0, const float* __restrict__ p1,
    const float* __restrict__ bias, const float* __restrict__ resid,
    const float* __restrict__ g, const float* __restrict__ b,
    float* __restrict__ xf, unsigned short* __restrict__ xb)
{
    const int row  = blockIdx.x * 4 + (threadIdx.x >> 6);
    const int lane = threadIdx.x & 63;
    f32x4 v[4];
    #pragma unroll
    for (int i = 0; i < 4; ++i) {
        const int col = i * 256 + lane * 4;
        const size_t o = (size_t)row * 1024 + col;
        f32x4 a0 = *reinterpret_cast<const f32x4*>(&p0[o]);
        f32x4 a1 = *reinterpret_cast<const f32x4*>(&p1[o]);
        f32x4 bs = *reinterpret_cast<const f32x4*>(&bias[col]);
        f32x4 rs = *reinterpret_cast<const f32x4*>(&resid[o]);
        v[i] = a0 + a1 + bs + rs;
    }
    ln_body(v, row, lane, g, b, xf, xb);
}

__global__ __launch_bounds__(256) void cvt_bf16(
    const float* __restrict__ in, unsigned short* __restrict__ out, int n)
{
    const int i = (blockIdx.x * 256 + threadIdx.x) * 4;
    if (i >= n) return;
    f32x4 v = *reinterpret_cast<const f32x4*>(&in[i]);
    u16x4 pk;
    #pragma unroll
    for (int j = 0; j < 4; ++j) pk[j] = f2bf(v[j]);
    *reinterpret_cast<u16x4*>(&out[i]) = pk;
}

// ---------------------------------------------------------------------------
// Per-layer weight pack (fp32->bf16, Q-scale folded):
//   [0,3DD) sa qkv  [3DD,6DD) ca qkv  [6DD,7DD) sa_wo  [7DD,8DD) ca_wo
//   [8DD,12DD) w1   [12DD,16DD) w2
// ---------------------------------------------------------------------------
__global__ __launch_bounds__(256) void pack_layer_w(
    const float* __restrict__ sa_wq, const float* __restrict__ sa_wk, const float* __restrict__ sa_wv,
    const float* __restrict__ ca_wq, const float* __restrict__ ca_wk, const float* __restrict__ ca_wv,
    const float* __restrict__ sa_wo, const float* __restrict__ ca_wo,
    const float* __restrict__ w1,   const float* __restrict__ w2,
    unsigned short* __restrict__ dst, int layer)
{
    const size_t DD = 1024u * 1024u;
    const size_t e  = ((size_t)blockIdx.x * 256 + threadIdx.x) * 4;
    const float* src;
    float scale = 1.f;
    if (e < 3 * DD) {
        const int part = (int)(e / DD);
        src = (part == 0 ? sa_wq : part == 1 ? sa_wk : sa_wv) + layer * DD + (e % DD);
        if (part == 0) scale = 0.125f;
    } else if (e < 6 * DD) {
        const size_t r = e - 3 * DD;
        const int part = (int)(r / DD);
        src = (part == 0 ? ca_wq : part == 1 ? ca_wk : ca_wv) + layer * DD + (r % DD);
        if (part == 0) scale = 0.125f;
    } else if (e < 7 * DD)  { src = sa_wo + layer * DD + (e - 6 * DD); }
    else if (e < 8 * DD)    { src = ca_wo + layer * DD + (e - 7 * DD); }
    else if (e < 12 * DD)   { src = w1 + (size_t)layer * 4 * DD + (e - 8 * DD); }
    else                    { src = w2 + (size_t)layer * 4 * DD + (e - 12 * DD); }
    f32x4 v = *reinterpret_cast<const f32x4*>(src);
    u16x4 pk;
    #pragma unroll
    for (int j = 0; j < 4; ++j) pk[j] = f2bf(v[j] * scale);
    *reinterpret_cast<u16x4*>(&dst[e]) = pk;
}

__global__ __launch_bounds__(256) void pack_bias(
    const float* __restrict__ sa_bq, const float* __restrict__ sa_bk, const float* __restrict__ sa_bv,
    const float* __restrict__ ca_bq, const float* __restrict__ ca_bk, const float* __restrict__ ca_bv,
    float* __restrict__ sab, float* __restrict__ cab)
{
    const int idx = blockIdx.x * 256 + threadIdx.x;
    const int half = idx / 12288;
    const int r    = idx % 12288;
    const int l    = r / 3072;
    const int pc   = r % 3072;
    const int part = pc >> 10;
    const int c    = pc & 1023;
    const float* src = half == 0 ? (part == 0 ? sa_bq : part == 1 ? sa_bk : sa_bv)
                                 : (part == 0 ? ca_bq : part == 1 ? ca_bk : ca_bv);
    const float v = src[l * 1024 + c] * (part == 0 ? 0.125f : 1.f);
    (half ? cab : sab)[l * 3072 + pc] = v;
}

// ---------------------------------------------------------------------------
extern "C" void kernel_launch(void* const* d_in, const int* in_sizes, int n_in,
                              void* d_out, int out_size, void* d_ws, size_t ws_size,
                              hipStream_t stream)
{
    (void)in_sizes; (void)n_in; (void)out_size; (void)ws_size;
    const int M  = 4096;
    const int Dm = 1024;
    const size_t DD = (size_t)Dm * Dm;

    const float* tgt   = (const float*)d_in[0];
    const float* mem   = (const float*)d_in[1];
    const float* sa_wq = (const float*)d_in[2];
    const float* sa_wk = (const float*)d_in[3];
    const float* sa_wv = (const float*)d_in[4];
    const float* sa_wo = (const float*)d_in[5];
    const float* sa_bq = (const float*)d_in[6];
    const float* sa_bk = (const float*)d_in[7];
    const float* sa_bv = (const float*)d_in[8];
    const float* sa_bo = (const float*)d_in[9];
    const float* ca_wq = (const float*)d_in[10];
    const float* ca_wk = (const float*)d_in[11];
    const float* ca_wv = (const float*)d_in[12];
    const float* ca_wo = (const float*)d_in[13];
    const float* ca_bq = (const float*)d_in[14];
    const float* ca_bk = (const float*)d_in[15];
    const float* ca_bv = (const float*)d_in[16];
    const float* ca_bo = (const float*)d_in[17];
    const float* w1    = (const float*)d_in[18];
    const float* b1    = (const float*)d_in[19];
    const float* w2    = (const float*)d_in[20];
    const float* b2    = (const float*)d_in[21];
    const float* ln1g  = (const float*)d_in[22];
    const float* ln1b  = (const float*)d_in[23];
    const float* ln2g  = (const float*)d_in[24];
    const float* ln2b  = (const float*)d_in[25];
    const float* ln3g  = (const float*)d_in[26];
    const float* ln3b  = (const float*)d_in[27];
    const float* lnfg  = (const float*)d_in[28];
    const float* lnfb  = (const float*)d_in[29];

    char* p = (char*)d_ws;
    float*          x_f    = (float*)p;          p += (size_t)M * Dm * 4;
    unsigned short* x_b    = (unsigned short*)p; p += (size_t)M * Dm * 2;
    unsigned short* mem_b  = (unsigned short*)p; p += (size_t)M * Dm * 2;
    unsigned short* qkv_b  = (unsigned short*)p; p += (size_t)M * 3072 * 2;
    unsigned short* cakv_b = (unsigned short*)p; p += (size_t)M * 2048 * 2;
    unsigned short* caq_b  = (unsigned short*)p; p += (size_t)M * Dm * 2;
    unsigned short* ao_b   = (unsigned short*)p; p += (size_t)M * Dm * 2;
    unsigned short* wpack  = (unsigned short*)p; p += 16 * DD * 2;
    float*          sab    = (float*)p;          p += 4 * 3072 * 4;
    float*          cab    = (float*)p;          p += 4 * 3072 * 4;
    unsigned short* h_b    = qkv_b;                                          // [4096][4096] bf16
    float*          par0   = (float*)((char*)qkv_b + (size_t)M * 4096 * 2);  // dead cakv tail+caq+ao
    float*          par1   = (float*)wpack;                                  // dead packed weights
    float*          z_f    = (float*)d_out;

    dim3 blk(256);
    auto gemm64 = [&](const unsigned short* A, const unsigned short* Bw, const float* bias,
                      const float* resid, unsigned short* ob, float* of, int N, int K, int mode) {
        dim3 grid(N / 128, M / 64);
        gemm_bt64<<<grid, blk, 0, stream>>>(A, Bw, bias, resid, ob, of, M, N, K, mode);
    };

    cvt_bf16<<<4096, blk, 0, stream>>>(tgt, x_b, M * Dm);
    cvt_bf16<<<4096, blk, 0, stream>>>(mem, mem_b, M * Dm);
    pack_bias<<<96, blk, 0, stream>>>(sa_bq, sa_bk, sa_bv, ca_bq, ca_bk, ca_bv, sab, cab);

    const float* res = tgt;
    for (int i = 0; i < 4; ++i) {
        pack_layer_w<<<16384, blk, 0, stream>>>(sa_wq, sa_wk, sa_wv, ca_wq, ca_wk, ca_wv,
                                                sa_wo, ca_wo, w1, w2, wpack, i);
        // --- self-attention (fused QKV, N=3072, grid 768 = 3 blocks/CU) ---
        gemm128<<<dim3(24, 32, 1), blk, 0, stream>>>(x_b, wpack, sab + i * 3072,
            qkv_b, nullptr, nullptr, 3072, 1024, 1024, 0);
        attn_fused<<<256, blk, 0, stream>>>(qkv_b, 3072, qkv_b + 1024, 3072, qkv_b + 2048, 3072, ao_b, 1);
        gemm64(ao_b, wpack + 6 * DD, sa_bo + i * Dm, res, nullptr, z_f, 1024, 1024, 2);
        ln_kernel<<<1024, blk, 0, stream>>>(z_f, ln1g + i * Dm, ln1b + i * Dm, x_f, x_b);
        res = x_f;
        // --- cross-attention (Q from x; fused KV from memory, N=2048) ---
        gemm64(x_b, wpack + 3 * DD, cab + i * 3072, nullptr, caq_b, nullptr, 1024, 1024, 0);
        gemm128<<<dim3(16, 32, 1), blk, 0, stream>>>(mem_b, wpack + 4 * DD, cab + i * 3072 + 1024,
            cakv_b, nullptr, nullptr, 2048, 1024, 1024, 0);
        attn_fused<<<256, blk, 0, stream>>>(caq_b, 1024, cakv_b, 2048, cakv_b + 1024, 2048, ao_b, 0);
        gemm64(ao_b, wpack + 7 * DD, ca_bo + i * Dm, x_f, nullptr, z_f, 1024, 1024, 2);
        ln_kernel<<<1024, blk, 0, stream>>>(z_f, ln2g + i * Dm, ln2b + i * Dm, x_f, x_b);
        // --- FFN (FFN1 grid 1024 = 4 blocks/CU; FFN2 split-K2 grid 512) ---
        gemm128<<<dim3(32, 32, 1), blk, 0, stream>>>(x_b, wpack + 8 * DD, b1 + i * 4096,
            h_b, nullptr, nullptr, 4096, 1024, 1024, 1);
        gemm128<<<dim3(8, 32, 2), blk, 0, stream>>>(h_b, wpack + 12 * DD, nullptr,
            nullptr, par0, par1, 1024, 4096, 2048, 3);
        ln_red2<<<1024, blk, 0, stream>>>(par0, par1, b2 + i * Dm, x_f,
            ln3g + i * Dm, ln3b + i * Dm, x_f, x_b);
    }
    ln_kernel<<<1024, blk, 0, stream>>>(x_f, lnfg, lnfb, (float*)d_out, nullptr);
}

// Round 8
// 1323.058 us; speedup vs baseline: 1.1504x; 1.0262x over previous
//
#include <hip/hip_runtime.h>

// ---------------------------------------------------------------------------
// 4-layer transformer decoder, bf16 MFMA implementation (round 8).
// gemm128 (proven r7 body): 128x128 tile, BK=32, dbuf, 4 blocks/CU.
//   - out-projections: split-K2 (mode 3) + reduce fused into ln_red2
//   - caQ+caKV: single dual-job dispatch (3 blocks/CU)
// attn: 128-thread blocks, T split -> 2 blocks/CU + causal tile-skip.
// ---------------------------------------------------------------------------

typedef __attribute__((ext_vector_type(4))) float f32x4;
typedef __attribute__((ext_vector_type(8))) short bf16x8;
typedef __attribute__((ext_vector_type(4))) unsigned short u16x4;
typedef __attribute__((ext_vector_type(4))) unsigned int   u32x4;

__device__ __forceinline__ unsigned short f2bf(float f) {
    unsigned int u = __builtin_bit_cast(unsigned int, f);
    u += 0x7fffu + ((u >> 16) & 1u);   // RNE
    return (unsigned short)(u >> 16);
}

__device__ __forceinline__ void gll16(const unsigned short* g, unsigned short* l) {
    auto* gp = reinterpret_cast<const __attribute__((address_space(1))) unsigned int*>(
        reinterpret_cast<uintptr_t>(g));
    auto* lp = reinterpret_cast<__attribute__((address_space(3))) unsigned int*>(
        reinterpret_cast<uintptr_t>(l));
    __builtin_amdgcn_global_load_lds(gp, lp, 16, 0, 0);
}

// ---------------------------------------------------------------------------
// Shared 128x128 GEMM body: A(bf16)[.][lda] rows m0..m0+127 @ B rows n0..,
// K range [kz, kz+klen). 4 waves (2x2), LDS 2x(128x32)/operand, slot-XOR swz.
// mode 0: bf16(acc+bias)  1: bf16(relu(acc+bias))  3: raw f32 -> po
// ---------------------------------------------------------------------------
__device__ __forceinline__ void gemm_body(
    const unsigned short* __restrict__ A,
    const unsigned short* __restrict__ Bw,
    const float* __restrict__ bias,
    unsigned short* __restrict__ outb,
    float* __restrict__ po,
    int N, int lda, int klen, int mode,
    int m0, int n0, int kz,
    unsigned short (*Al)[128 * 32], unsigned short (*Bl)[128 * 32])
{
    const int tid  = threadIdx.x;
    const int lane = tid & 63;
    const int w    = tid >> 6;
    const int wr   = (w >> 1) * 64;
    const int wc   = (w & 1) * 64;
    const int l15  = lane & 15;
    const int l4   = lane >> 4;

    const int srow = w * 16 + (lane >> 2);
    const int scol = ((lane & 3) ^ ((srow >> 1) & 3)) * 8;
    const unsigned short* ag = A  + (size_t)(m0 + srow) * lda + kz + scol;
    const unsigned short* bg = Bw + (size_t)(n0 + srow) * lda + kz + scol;
    const size_t jstep = (size_t)64 * lda;
    const int lbase = (w * 16) * 32;

    int aoff[4], boff[4];
    #pragma unroll
    for (int i = 0; i < 4; ++i) {
        const int ra = wr + i * 16 + l15;
        const int rb = wc + i * 16 + l15;
        aoff[i] = ra * 32 + ((l4 ^ ((ra >> 1) & 3)) * 8);
        boff[i] = rb * 32 + ((l4 ^ ((rb >> 1) & 3)) * 8);
    }

    f32x4 acc[4][4];
    #pragma unroll
    for (int mi = 0; mi < 4; ++mi)
        #pragma unroll
        for (int ni = 0; ni < 4; ++ni)
            acc[mi][ni] = (f32x4){0.f, 0.f, 0.f, 0.f};

    #pragma unroll
    for (int j = 0; j < 2; ++j) {
        gll16(ag + j * jstep, &Al[0][lbase + j * 64 * 32]);
        gll16(bg + j * jstep, &Bl[0][lbase + j * 64 * 32]);
    }
    __syncthreads();

    const int nt = klen >> 5;
    int cur = 0;
    for (int t = 0; t < nt; ++t) {
        if (t + 1 < nt) {
            ag += 32; bg += 32;
            #pragma unroll
            for (int j = 0; j < 2; ++j) {
                gll16(ag + j * jstep, &Al[cur ^ 1][lbase + j * 64 * 32]);
                gll16(bg + j * jstep, &Bl[cur ^ 1][lbase + j * 64 * 32]);
            }
        }
        const unsigned short* ac = &Al[cur][0];
        const unsigned short* bc = &Bl[cur][0];
        bf16x8 af[4], bf[4];
        #pragma unroll
        for (int i = 0; i < 4; ++i) af[i] = *reinterpret_cast<const bf16x8*>(&ac[aoff[i]]);
        #pragma unroll
        for (int i = 0; i < 4; ++i) bf[i] = *reinterpret_cast<const bf16x8*>(&bc[boff[i]]);
        #pragma unroll
        for (int mi = 0; mi < 4; ++mi)
            #pragma unroll
            for (int ni = 0; ni < 4; ++ni)
                acc[mi][ni] = __builtin_amdgcn_mfma_f32_16x16x32_bf16(af[mi], bf[ni], acc[mi][ni], 0, 0, 0);
        __syncthreads();
        cur ^= 1;
    }

    #pragma unroll
    for (int mi = 0; mi < 4; ++mi) {
        #pragma unroll
        for (int ni = 0; ni < 4; ++ni) {
            const int col = n0 + wc + ni * 16 + l15;
            const float bs = (mode == 3) ? 0.f : bias[col];
            #pragma unroll
            for (int r = 0; r < 4; ++r) {
                const int row = m0 + wr + mi * 16 + l4 * 4 + r;
                const float val = acc[mi][ni][r] + bs;
                if (mode == 0)      outb[(size_t)row * N + col] = f2bf(val);
                else if (mode == 1) outb[(size_t)row * N + col] = f2bf(fmaxf(val, 0.f));
                else                po[(size_t)row * N + col] = val;
            }
        }
    }
}

// gemm128: standard launch; XCD band swizzle (gy == 32, nwg % 8 == 0);
// split-K via blockIdx.z -> outf0/outf1.
__global__ __launch_bounds__(256, 4) void gemm128(
    const unsigned short* __restrict__ A,
    const unsigned short* __restrict__ Bw,
    const float* __restrict__ bias,
    unsigned short* __restrict__ outb,
    float* __restrict__ outf0,
    float* __restrict__ outf1,
    int N, int lda, int klen, int mode)
{
    __shared__ unsigned short Al[2][128 * 32];
    __shared__ unsigned short Bl[2][128 * 32];
    const int gx   = gridDim.x;
    const int orig = blockIdx.y * gx + blockIdx.x;
    const int xcd  = orig & 7;
    const int lin  = orig >> 3;
    const int m0   = (xcd * 4 + (lin & 3)) * 128;
    const int n0   = (lin >> 2) * 128;
    const int kz   = blockIdx.z * klen;
    float* po = (blockIdx.z == 0) ? outf0 : outf1;
    gemm_body(A, Bw, bias, outb, po, N, lda, klen, mode, m0, n0, kz, Al, Bl);
}

// gemm128_ca: dual-job dispatch, all mode 0. blockIdx.x<8 -> job0 (N0=1024),
// else job1 (N1=2048). Per-job XCD band swizzle.
__global__ __launch_bounds__(256, 4) void gemm128_ca(
    const unsigned short* __restrict__ A0, const unsigned short* __restrict__ A1,
    const unsigned short* __restrict__ B0, const unsigned short* __restrict__ B1,
    const float* __restrict__ bias0, const float* __restrict__ bias1,
    unsigned short* __restrict__ out0, unsigned short* __restrict__ out1,
    int lda, int klen)
{
    __shared__ unsigned short Al[2][128 * 32];
    __shared__ unsigned short Bl[2][128 * 32];
    const int grp = (blockIdx.x >= 8);
    const int bx  = blockIdx.x - (grp ? 8 : 0);
    const int lgx = grp ? 16 : 8;
    const int orig = blockIdx.y * lgx + bx;
    const int xcd  = orig & 7;
    const int lin  = orig >> 3;
    const int m0   = (xcd * 4 + (lin & 3)) * 128;
    const int n0   = (lin >> 2) * 128;
    gemm_body(grp ? A1 : A0, grp ? B1 : B0, grp ? bias1 : bias0,
              grp ? out1 : out0, nullptr, grp ? 2048 : 1024, lda, klen, 0,
              m0, n0, 0, Al, Bl);
}

// ---------------------------------------------------------------------------
// Fused attention: 128-thread blocks (2 waves), grid 512 = (n,h,thalf).
// Each block: T rows [thalf*128, +128), full K/V staged. LDS 80 KB -> 2/CU.
// Causal: wave-uniform tile-skip in QK (fully-masked s-tiles) and PV
// (P rows exactly 0 beyond the diagonal tile: exp(-1e9 - mx) flushes to 0).
// ---------------------------------------------------------------------------
__global__ __launch_bounds__(128) void attn_fused(
    const unsigned short* __restrict__ Q, int qs,
    const unsigned short* __restrict__ Kb, int ks_,
    const unsigned short* __restrict__ Vb, int vs,
    unsigned short* __restrict__ O,
    int causal)
{
    __shared__ unsigned short Kl[8][256][8];        // 32 KB
    __shared__ unsigned short Vt[32][64][8];        // 32 KB
    __shared__ unsigned short Pl[2][32][16][8];     // 16 KB
    const int tid   = threadIdx.x;
    const int lane  = tid & 63;
    const int w     = tid >> 6;                     // 0..1
    const int bxi   = blockIdx.x;
    const int n     = bxi >> 5;
    const int h     = (bxi >> 1) & 15;
    const int thalf = bxi & 1;
    const int l15   = lane & 15;
    const int l4    = lane >> 4;
    const size_t hoff = (size_t)h * 64;

    #pragma unroll
    for (int i = 0; i < 16; ++i) {
        const int e = i * 128 + tid;
        const int s = e >> 3;
        const int c = e & 7;
        u32x4 kv = *reinterpret_cast<const u32x4*>(&Kb[((size_t)s * 16 + n) * ks_ + hoff + c * 8]);
        *reinterpret_cast<u32x4*>(&Kl[c][s][0]) = kv;
        u32x4 vv = *reinterpret_cast<const u32x4*>(&Vb[((size_t)s * 16 + n) * vs + hoff + c * 8]);
        const unsigned short* ve = reinterpret_cast<const unsigned short*>(&vv);
        #pragma unroll
        for (int j = 0; j < 8; ++j)
            Vt[s >> 3][c * 8 + j][s & 7] = ve[j];
    }
    __syncthreads();

    for (int ch = 0; ch < 4; ++ch) {
        const int t0 = thalf * 128 + w * 64 + ch * 16;
        bf16x8 qa[2];
        #pragma unroll
        for (int ks = 0; ks < 2; ++ks)
            qa[ks] = *reinterpret_cast<const bf16x8*>(
                &Q[((size_t)(t0 + l15) * 16 + n) * qs + hoff + ks * 32 + l4 * 8]);

        f32x4 sc[16];
        #pragma unroll
        for (int st = 0; st < 16; ++st) {
            if (causal && st * 16 > t0 + 15) {       // fully masked tile: skip MFMA
                sc[st] = (f32x4){-1e9f, -1e9f, -1e9f, -1e9f};
                continue;
            }
            f32x4 a = (f32x4){0.f, 0.f, 0.f, 0.f};
            #pragma unroll
            for (int ks = 0; ks < 2; ++ks) {
                bf16x8 kf = *reinterpret_cast<const bf16x8*>(&Kl[ks * 4 + l4][st * 16 + l15][0]);
                a = __builtin_amdgcn_mfma_f32_16x16x32_bf16(qa[ks], kf, a, 0, 0, 0);
            }
            sc[st] = a;
        }
        if (causal) {
            #pragma unroll
            for (int st = 0; st < 16; ++st) {
                const int sg = st * 16 + l15;
                #pragma unroll
                for (int r = 0; r < 4; ++r) {
                    const int tg = t0 + l4 * 4 + r;
                    if (sg > tg) sc[st][r] = -1e9f;
                }
            }
        }
        #pragma unroll
        for (int r = 0; r < 4; ++r) {
            float mx = -3.0e38f;
            #pragma unroll
            for (int st = 0; st < 16; ++st) mx = fmaxf(mx, sc[st][r]);
            #pragma unroll
            for (int dd = 1; dd < 16; dd <<= 1) mx = fmaxf(mx, __shfl_xor(mx, dd, 64));
            float sum = 0.f;
            #pragma unroll
            for (int st = 0; st < 16; ++st) {
                const float e = __expf(sc[st][r] - mx);
                sc[st][r] = e;
                sum += e;
            }
            #pragma unroll
            for (int dd = 1; dd < 16; dd <<= 1) sum += __shfl_xor(sum, dd, 64);
            const float inv = 1.f / sum;
            const int rl = l4 * 4 + r;
            #pragma unroll
            for (int st = 0; st < 16; ++st) {
                const int sg = st * 16 + l15;
                Pl[w][sg >> 3][rl][sg & 7] = f2bf(sc[st][r] * inv);
            }
        }
        f32x4 oacc[4];
        #pragma unroll
        for (int dt = 0; dt < 4; ++dt) oacc[dt] = (f32x4){0.f, 0.f, 0.f, 0.f};
        #pragma unroll
        for (int kt = 0; kt < 8; ++kt) {
            if (causal && kt * 32 > t0 + 15) continue;   // P exactly 0 there
            bf16x8 pa = *reinterpret_cast<const bf16x8*>(&Pl[w][kt * 4 + l4][l15][0]);
            #pragma unroll
            for (int dt = 0; dt < 4; ++dt) {
                bf16x8 vf = *reinterpret_cast<const bf16x8*>(&Vt[kt * 4 + l4][dt * 16 + l15][0]);
                oacc[dt] = __builtin_amdgcn_mfma_f32_16x16x32_bf16(pa, vf, oacc[dt], 0, 0, 0);
            }
        }
        #pragma unroll
        for (int dt = 0; dt < 4; ++dt)
            #pragma unroll
            for (int r = 0; r < 4; ++r)
                O[((size_t)(t0 + l4 * 4 + r) * 16 + n) * 1024 + hoff + dt * 16 + l15] = f2bf(oacc[dt][r]);
    }
}

// ---------------------------------------------------------------------------
// LayerNorm over D=1024, one wave per row (plain and fused-reduce variants)
// ---------------------------------------------------------------------------
__device__ __forceinline__ void ln_body(
    f32x4 (&v)[4], int row, int lane,
    const float* __restrict__ g, const float* __restrict__ b,
    float* __restrict__ xf, unsigned short* __restrict__ xb)
{
    float s = 0.f;
    #pragma unroll
    for (int i = 0; i < 4; ++i) s += v[i][0] + v[i][1] + v[i][2] + v[i][3];
    #pragma unroll
    for (int dd = 1; dd < 64; dd <<= 1) s += __shfl_xor(s, dd, 64);
    const float mu = s * (1.f / 1024.f);
    float q = 0.f;
    #pragma unroll
    for (int i = 0; i < 4; ++i)
        #pragma unroll
        for (int j = 0; j < 4; ++j) { const float d0 = v[i][j] - mu; q += d0 * d0; }
    #pragma unroll
    for (int dd = 1; dd < 64; dd <<= 1) q += __shfl_xor(q, dd, 64);
    const float rstd = rsqrtf(q * (1.f / 1024.f) + 1e-5f);
    #pragma unroll
    for (int i = 0; i < 4; ++i) {
        const int col = i * 256 + lane * 4;
        f32x4 gg = *reinterpret_cast<const f32x4*>(&g[col]);
        f32x4 bb = *reinterpret_cast<const f32x4*>(&b[col]);
        f32x4 y;
        #pragma unroll
        for (int j = 0; j < 4; ++j) y[j] = (v[i][j] - mu) * rstd * gg[j] + bb[j];
        if (xf) *reinterpret_cast<f32x4*>(&xf[(size_t)row * 1024 + col]) = y;
        if (xb) {
            u16x4 pk;
            #pragma unroll
            for (int j = 0; j < 4; ++j) pk[j] = f2bf(y[j]);
            *reinterpret_cast<u16x4*>(&xb[(size_t)row * 1024 + col]) = pk;
        }
    }
}

__global__ __launch_bounds__(256) void ln_kernel(
    const float* __restrict__ z, const float* __restrict__ g, const float* __restrict__ b,
    float* __restrict__ xf, unsigned short* __restrict__ xb)
{
    const int row  = blockIdx.x * 4 + (threadIdx.x >> 6);
    const int lane = threadIdx.x & 63;
    f32x4 v[4];
    #pragma unroll
    for (int i = 0; i < 4; ++i)
        v[i] = *reinterpret_cast<const f32x4*>(&z[(size_t)row * 1024 + i * 256 + lane * 4]);
    ln_body(v, row, lane, g, b, xf, xb);
}

// z = p0 + p1 + bias + resid, then LN. resid may alias xf (row-local).
__global__ __launch_bounds__(256) void ln_red2(
    const float* __restrict__ p0, const float* __restrict__ p1,
    const float* __restrict__ bias, const float* __restrict__ resid,
    const float* __restrict__ g, const float* __restrict__ b,
    float* __restrict__ xf, unsigned short* __restrict__ xb)
{
    const int row  = blockIdx.x * 4 + (threadIdx.x >> 6);
    const int lane = threadIdx.x & 63;
    f32x4 v[4];
    #pragma unroll
    for (int i = 0; i < 4; ++i) {
        const int col = i * 256 + lane * 4;
        const size_t o = (size_t)row * 1024 + col;
        f32x4 a0 = *reinterpret_cast<const f32x4*>(&p0[o]);
        f32x4 a1 = *reinterpret_cast<const f32x4*>(&p1[o]);
        f32x4 bs = *reinterpret_cast<const f32x4*>(&bias[col]);
        f32x4 rs = *reinterpret_cast<const f32x4*>(&resid[o]);
        v[i] = a0 + a1 + bs + rs;
    }
    ln_body(v, row, lane, g, b, xf, xb);
}

__global__ __launch_bounds__(256) void cvt_bf16(
    const float* __restrict__ in, unsigned short* __restrict__ out, int n)
{
    const int i = (blockIdx.x * 256 + threadIdx.x) * 4;
    if (i >= n) return;
    f32x4 v = *reinterpret_cast<const f32x4*>(&in[i]);
    u16x4 pk;
    #pragma unroll
    for (int j = 0; j < 4; ++j) pk[j] = f2bf(v[j]);
    *reinterpret_cast<u16x4*>(&out[i]) = pk;
}

// ---------------------------------------------------------------------------
// Per-layer weight pack (fp32->bf16, Q-scale folded):
//   [0,3DD) sa qkv  [3DD,6DD) ca qkv  [6DD,7DD) sa_wo  [7DD,8DD) ca_wo
//   [8DD,12DD) w1   [12DD,16DD) w2
// ---------------------------------------------------------------------------
__global__ __launch_bounds__(256) void pack_layer_w(
    const float* __restrict__ sa_wq, const float* __restrict__ sa_wk, const float* __restrict__ sa_wv,
    const float* __restrict__ ca_wq, const float* __restrict__ ca_wk, const float* __restrict__ ca_wv,
    const float* __restrict__ sa_wo, const float* __restrict__ ca_wo,
    const float* __restrict__ w1,   const float* __restrict__ w2,
    unsigned short* __restrict__ dst, int layer)
{
    const size_t DD = 1024u * 1024u;
    const size_t e  = ((size_t)blockIdx.x * 256 + threadIdx.x) * 4;
    const float* src;
    float scale = 1.f;
    if (e < 3 * DD) {
        const int part = (int)(e / DD);
        src = (part == 0 ? sa_wq : part == 1 ? sa_wk : sa_wv) + layer * DD + (e % DD);
        if (part == 0) scale = 0.125f;
    } else if (e < 6 * DD) {
        const size_t r = e - 3 * DD;
        const int part = (int)(r / DD);
        src = (part == 0 ? ca_wq : part == 1 ? ca_wk : ca_wv) + layer * DD + (r % DD);
        if (part == 0) scale = 0.125f;
    } else if (e < 7 * DD)  { src = sa_wo + layer * DD + (e - 6 * DD); }
    else if (e < 8 * DD)    { src = ca_wo + layer * DD + (e - 7 * DD); }
    else if (e < 12 * DD)   { src = w1 + (size_t)layer * 4 * DD + (e - 8 * DD); }
    else                    { src = w2 + (size_t)layer * 4 * DD + (e - 12 * DD); }
    f32x4 v = *reinterpret_cast<const f32x4*>(src);
    u16x4 pk;
    #pragma unroll
    for (int j = 0; j < 4; ++j) pk[j] = f2bf(v[j] * scale);
    *reinterpret_cast<u16x4*>(&dst[e]) = pk;
}

__global__ __launch_bounds__(256) void pack_bias(
    const float* __restrict__ sa_bq, const float* __restrict__ sa_bk, const float* __restrict__ sa_bv,
    const float* __restrict__ ca_bq, const float* __restrict__ ca_bk, const float* __restrict__ ca_bv,
    float* __restrict__ sab, float* __restrict__ cab)
{
    const int idx = blockIdx.x * 256 + threadIdx.x;
    const int half = idx / 12288;
    const int r    = idx % 12288;
    const int l    = r / 3072;
    const int pc   = r % 3072;
    const int part = pc >> 10;
    const int c    = pc & 1023;
    const float* src = half == 0 ? (part == 0 ? sa_bq : part == 1 ? sa_bk : sa_bv)
                                 : (part == 0 ? ca_bq : part == 1 ? ca_bk : ca_bv);
    const float v = src[l * 1024 + c] * (part == 0 ? 0.125f : 1.f);
    (half ? cab : sab)[l * 3072 + pc] = v;
}

// ---------------------------------------------------------------------------
extern "C" void kernel_launch(void* const* d_in, const int* in_sizes, int n_in,
                              void* d_out, int out_size, void* d_ws, size_t ws_size,
                              hipStream_t stream)
{
    (void)in_sizes; (void)n_in; (void)out_size; (void)ws_size;
    const int M  = 4096;
    const int Dm = 1024;
    const size_t DD = (size_t)Dm * Dm;

    const float* tgt   = (const float*)d_in[0];
    const float* mem   = (const float*)d_in[1];
    const float* sa_wq = (const float*)d_in[2];
    const float* sa_wk = (const float*)d_in[3];
    const float* sa_wv = (const float*)d_in[4];
    const float* sa_wo = (const float*)d_in[5];
    const float* sa_bq = (const float*)d_in[6];
    const float* sa_bk = (const float*)d_in[7];
    const float* sa_bv = (const float*)d_in[8];
    const float* sa_bo = (const float*)d_in[9];
    const float* ca_wq = (const float*)d_in[10];
    const float* ca_wk = (const float*)d_in[11];
    const float* ca_wv = (const float*)d_in[12];
    const float* ca_wo = (const float*)d_in[13];
    const float* ca_bq = (const float*)d_in[14];
    const float* ca_bk = (const float*)d_in[15];
    const float* ca_bv = (const float*)d_in[16];
    const float* ca_bo = (const float*)d_in[17];
    const float* w1    = (const float*)d_in[18];
    const float* b1    = (const float*)d_in[19];
    const float* w2    = (const float*)d_in[20];
    const float* b2    = (const float*)d_in[21];
    const float* ln1g  = (const float*)d_in[22];
    const float* ln1b  = (const float*)d_in[23];
    const float* ln2g  = (const float*)d_in[24];
    const float* ln2b  = (const float*)d_in[25];
    const float* ln3g  = (const float*)d_in[26];
    const float* ln3b  = (const float*)d_in[27];
    const float* lnfg  = (const float*)d_in[28];
    const float* lnfb  = (const float*)d_in[29];

    char* p = (char*)d_ws;
    float*          x_f    = (float*)p;          p += (size_t)M * Dm * 4;       // 16.78 MB
    unsigned short* x_b    = (unsigned short*)p; p += (size_t)M * Dm * 2;
    unsigned short* mem_b  = (unsigned short*)p; p += (size_t)M * Dm * 2;
    unsigned short* qkv_b  = (unsigned short*)p; p += (size_t)M * 3072 * 2;     // 25.17 MB
    unsigned short* cakv_b = (unsigned short*)p; p += (size_t)M * 2048 * 2;     // 16.78 MB
    unsigned short* caq_b  = (unsigned short*)p; p += (size_t)M * Dm * 2;
    unsigned short* ao_b   = (unsigned short*)p; p += (size_t)M * Dm * 2;
    unsigned short* wpack  = (unsigned short*)p; p += 16 * DD * 2;              // 33.55 MB
    float*          sab    = (float*)p;          p += 4 * 3072 * 4;
    float*          cab    = (float*)p;          p += 4 * 3072 * 4;
    unsigned short* h_b    = qkv_b;                                             // [4096][4096] bf16
    // out-proj split-K partials (live only between gemm and ln_red2):
    float*          parA   = (float*)qkv_b;                                     // 16.78 MB (dead Q/K/V)
    float*          parB   = (float*)cakv_b;                                    // 16.78 MB (dead ca K/V)
    // FFN2 partials (h_b spans qkv_b + first 8.4 MB of cakv_b):
    float*          par0   = (float*)((char*)qkv_b + (size_t)M * 4096 * 2);     // cakv tail + caq
    float*          par1   = (float*)wpack;                                     // dead packed weights

    dim3 blk(256), blkA(128);

    cvt_bf16<<<4096, blk, 0, stream>>>(tgt, x_b, M * Dm);
    cvt_bf16<<<4096, blk, 0, stream>>>(mem, mem_b, M * Dm);
    pack_bias<<<96, blk, 0, stream>>>(sa_bq, sa_bk, sa_bv, ca_bq, ca_bk, ca_bv, sab, cab);

    const float* res = tgt;
    for (int i = 0; i < 4; ++i) {
        pack_layer_w<<<16384, blk, 0, stream>>>(sa_wq, sa_wk, sa_wv, ca_wq, ca_wk, ca_wv,
                                                sa_wo, ca_wo, w1, w2, wpack, i);
        // --- self-attention ---
        gemm128<<<dim3(24, 32, 1), blk, 0, stream>>>(x_b, wpack, sab + i * 3072,
            qkv_b, nullptr, nullptr, 3072, 1024, 1024, 0);
        attn_fused<<<512, blkA, 0, stream>>>(qkv_b, 3072, qkv_b + 1024, 3072, qkv_b + 2048, 3072, ao_b, 1);
        gemm128<<<dim3(8, 32, 2), blk, 0, stream>>>(ao_b, wpack + 6 * DD, nullptr,
            nullptr, parA, parB, 1024, 1024, 512, 3);
        ln_red2<<<1024, blk, 0, stream>>>(parA, parB, sa_bo + i * Dm, res,
            ln1g + i * Dm, ln1b + i * Dm, x_f, x_b);
        res = x_f;
        // --- cross-attention (caQ + caKV in ONE dispatch) ---
        gemm128_ca<<<dim3(24, 32, 1), blk, 0, stream>>>(x_b, mem_b,
            wpack + 3 * DD, wpack + 4 * DD,
            cab + i * 3072, cab + i * 3072 + 1024,
            caq_b, cakv_b, 1024, 1024);
        attn_fused<<<512, blkA, 0, stream>>>(caq_b, 1024, cakv_b, 2048, cakv_b + 1024, 2048, ao_b, 0);
        gemm128<<<dim3(8, 32, 2), blk, 0, stream>>>(ao_b, wpack + 7 * DD, nullptr,
            nullptr, parA, parB, 1024, 1024, 512, 3);
        ln_red2<<<1024, blk, 0, stream>>>(parA, parB, ca_bo + i * Dm, x_f,
            ln2g + i * Dm, ln2b + i * Dm, x_f, x_b);
        // --- FFN ---
        gemm128<<<dim3(32, 32, 1), blk, 0, stream>>>(x_b, wpack + 8 * DD, b1 + i * 4096,
            h_b, nullptr, nullptr, 4096, 1024, 1024, 1);
        gemm128<<<dim3(8, 32, 2), blk, 0, stream>>>(h_b, wpack + 12 * DD, nullptr,
            nullptr, par0, par1, 1024, 4096, 2048, 3);
        ln_red2<<<1024, blk, 0, stream>>>(par0, par1, b2 + i * Dm, x_f,
            ln3g + i * Dm, ln3b + i * Dm, x_f, x_b);
    }
    ln_kernel<<<1024, blk, 0, stream>>>(x_f, lnfg, lnfb, (float*)d_out, nullptr);
}